// Round 11
// baseline (422.259 us; speedup 1.0000x reference)
//
#include <hip/hip_runtime.h>
#include <stdint.h>
#include <math.h>

// MultiGeometryAttention — f32 in/out. B=2 T=2048 C=1024 H=16 HD=64.
// heads 0-5 sdpa(0.125) | 6-9 hyperbolic(curvature) | 10-15 cos-normalized sdpa(8).
// Split-bf16 (no fp32 MFMA): x*W via A'=[hi|lo|hi],B'=[hi|hi|lo] K'=3K GEMM.
// Attention: static-max softmax, split-K partials, fragment-linear tiles.
// R11: (a) 2-product scores (qh+ql)·kh — score err ~2e-3, hyperbolic insensitive
//      (ds/d(dot)~8e-4); K staging bytes -50%, S-MFMA 48->32.
//      (b) per-wave LDS DOUBLE-BUFFER via global_load_lds (zero VGPR cost),
//      barrier-free: explicit s_waitcnt vmcnt(0) waits on copies issued a full
//      iteration earlier. R9 proved prefetch cuts ktile latency 10.4k->6.2k cyc
//      but VGPR cost killed residency; async-LDS gets the prefetch for free.
//      LDS/wave = 2x16KB + 4KB P = 36KB -> 4 waves/CU.
// WS (proven peak 94,896,128 B): layout identical to R8/R10.

typedef __bf16 bf16x8 __attribute__((ext_vector_type(8)));
typedef float f32x4 __attribute__((ext_vector_type(4)));

static __device__ __forceinline__ float bf2f(unsigned short u) {
  union { unsigned int i; float f; } v; v.i = ((unsigned int)u) << 16; return v.f;
}
static __device__ __forceinline__ unsigned short f2bf(float f) {
  union { float f; unsigned int i; } v; v.f = f;
  unsigned int x = v.i;
  x += 0x7fffu + ((x >> 16) & 1u);   // RNE
  return (unsigned short)(x >> 16);
}

// direct global->LDS async copy, 16B/lane. LDS dest must be uniform + lane*16.
static __device__ __forceinline__ void async_copy16(const void* gsrc, void* ldst) {
  auto* lp = reinterpret_cast<__attribute__((address_space(3))) unsigned int*>(
      reinterpret_cast<uintptr_t>(ldst));
  auto* gp = reinterpret_cast<const __attribute__((address_space(1))) unsigned int*>(
      reinterpret_cast<uintptr_t>(gsrc));
  __builtin_amdgcn_global_load_lds(gp, lp, 16, 0, 0);
}

// s_waitcnt vmcnt(0), lgkm/exp unconstrained: simm = (0xF<<8)|(0x7<<4)|0 = 0x0F70.
static __device__ __forceinline__ void wait_vm0() {
  asm volatile("" ::: "memory");
  __builtin_amdgcn_s_waitcnt(0x0F70);
  asm volatile("" ::: "memory");
}

// f32 [rows][1024] -> split bf16 [rows][3072]. PAT=0 (A): [hi|lo|hi]; PAT=1 (B): [hi|hi|lo].
template <int PAT>
__global__ __launch_bounds__(256) void split3(const float* __restrict__ in,
                                              unsigned short* __restrict__ out) {
  const int row = blockIdx.x;
  const int kq = threadIdx.x * 4;
  const f32x4 x = *(const f32x4*)(in + (size_t)row * 1024 + kq);
  unsigned short hi[4], lo[4];
#pragma unroll
  for (int i = 0; i < 4; ++i) {
    hi[i] = f2bf(x[i]);
    lo[i] = f2bf(x[i] - bf2f(hi[i]));   // exact residual in f32
  }
  uint2 uh, ul;
  uh.x = (unsigned)hi[0] | ((unsigned)hi[1] << 16);
  uh.y = (unsigned)hi[2] | ((unsigned)hi[3] << 16);
  ul.x = (unsigned)lo[0] | ((unsigned)lo[1] << 16);
  ul.y = (unsigned)lo[2] | ((unsigned)lo[3] << 16);
  unsigned short* op = out + (size_t)row * 3072 + kq;
  *(uint2*)(op)        = uh;
  *(uint2*)(op + 1024) = PAT ? uh : ul;
  *(uint2*)(op + 2048) = PAT ? ul : uh;
}

// C[m][n] = sum_k A[m][k]*B[n][k] (+bias[n]) -> f32. 128x128 tile, BK=64, 4 waves,
// 16x16x32 bf16 MFMA, XOR-swizzled LDS (verified).
template <int HASBIAS>
__global__ __launch_bounds__(256) void gemm_bt(
    const unsigned short* __restrict__ A, const unsigned short* __restrict__ Bm,
    float* __restrict__ C, const float* __restrict__ bias, int N_, int K_) {
  alignas(16) __shared__ unsigned short smA[128 * 64];
  alignas(16) __shared__ unsigned short smB[128 * 64];
  const int tid = threadIdx.x;
  const int lane = tid & 63;
  const int wv = tid >> 6;
  const int wm = wv >> 1, wn = wv & 1;
  const long m0 = (long)blockIdx.y * 128, n0 = (long)blockIdx.x * 128;

  const f32x4 zero4 = {0.f, 0.f, 0.f, 0.f};
  f32x4 acc[4][4];
#pragma unroll
  for (int i = 0; i < 4; ++i)
#pragma unroll
    for (int j = 0; j < 4; ++j) acc[i][j] = zero4;

  int mrow[4], gg[4];
#pragma unroll
  for (int w = 0; w < 4; ++w) {
    int c = w * 256 + tid;
    mrow[w] = c >> 3;
    gg[w] = (c & 7) ^ ((c >> 3) & 7);
  }

  const int kTiles = K_ >> 6;
  for (int kt = 0; kt < kTiles; ++kt) {
    if (kt) __syncthreads();
    const int kb = kt << 6;
#pragma unroll
    for (int w = 0; w < 4; ++w) {
      const int c = w * 256 + tid;
      async_copy16(A + (size_t)(m0 + mrow[w]) * K_ + kb + gg[w] * 8,
                   (char*)smA + c * 16);
      async_copy16(Bm + (size_t)(n0 + mrow[w]) * K_ + kb + gg[w] * 8,
                   (char*)smB + c * 16);
    }
    __syncthreads();
#pragma unroll
    for (int ks = 0; ks < 2; ++ks) {
      bf16x8 af[4], bg[4];
#pragma unroll
      for (int i = 0; i < 4; ++i) {
        const int ra = wm * 64 + i * 16 + (lane & 15);
        const int ga = (ks * 4 + (lane >> 4)) ^ (ra & 7);
        af[i] = *(const bf16x8*)((const char*)smA + ra * 128 + ga * 16);
        const int rb = wn * 64 + i * 16 + (lane & 15);
        const int gb2 = (ks * 4 + (lane >> 4)) ^ (rb & 7);
        bg[i] = *(const bf16x8*)((const char*)smB + rb * 128 + gb2 * 16);
      }
#pragma unroll
      for (int i = 0; i < 4; ++i)
#pragma unroll
        for (int j = 0; j < 4; ++j)
          acc[i][j] = __builtin_amdgcn_mfma_f32_16x16x32_bf16(af[i], bg[j], acc[i][j], 0, 0, 0);
    }
  }

  const int r0 = wm * 64 + (lane >> 4) * 4;
  const int c0 = wn * 64 + (lane & 15);
#pragma unroll
  for (int j = 0; j < 4; ++j) {
    const long col = n0 + c0 + j * 16;
    float bv = 0.f;
    if (HASBIAS) bv = bias[col];
#pragma unroll
    for (int i = 0; i < 4; ++i) {
#pragma unroll
      for (int r = 0; r < 4; ++r) {
        const long row = m0 + r0 + i * 16 + r;
        C[row * N_ + col] = acc[i][j][r] + bv;
      }
    }
  }
}

// prep: rotary q,k; norms; normalize h>=10; tq/tk for hyperbolic; emit FRAGMENT-LINEAR
// tiles (element (frag,quad,c15,j) at frag*512 + quad*128 + c15*8 + j).
__global__ __launch_bounds__(256) void prep(
    const float* __restrict__ qkvf, unsigned short* __restrict__ Q2,
    unsigned short* __restrict__ K2, unsigned short* __restrict__ V2,
    float* __restrict__ qq, float* __restrict__ kk, const float* __restrict__ curvg) {
  __shared__ unsigned short Vl[64 * 66];
  const int tid = threadIdx.x;
  const int zz = blockIdx.x;
  const int ttile = zz & 31, bh = zz >> 5;
  const int b = bh >> 4, h = bh & 15;
  const int t0 = ttile * 64;
  const int tr = tid >> 2, seg = tid & 3;
  const int t = t0 + tr;
  const float* src = qkvf + ((size_t)(b * 2048 + t)) * 3072 + h * 64 + seg * 16;

  float qv[16], kv[16], vv[16];
#pragma unroll
  for (int c = 0; c < 4; ++c) {
    const f32x4 a  = *(const f32x4*)(src + c * 4);
    const f32x4 bb = *(const f32x4*)(src + 1024 + c * 4);
    const f32x4 cc = *(const f32x4*)(src + 2048 + c * 4);
#pragma unroll
    for (int e = 0; e < 4; ++e) { qv[c*4+e] = a[e]; kv[c*4+e] = bb[e]; vv[c*4+e] = cc[e]; }
  }
  float qr[16], kr[16];
#pragma unroll
  for (int e = 0; e < 16; ++e) {
    const int d = seg * 16 + e;
    const int i = d & 31;
    const float invf = exp2f(-0.41524101186109286f * (float)i);  // 10000^(-i/32)
    float sn, cs;
    sincosf((float)t * invf, &sn, &cs);
    const float qo = __shfl_xor(qv[e], 2, 64);
    const float ko = __shfl_xor(kv[e], 2, 64);
    qr[e] = (d < 32) ? (qv[e] * cs + qo * sn) : (qv[e] * cs - qo * sn);
    kr[e] = (d < 32) ? (kv[e] * cs + ko * sn) : (kv[e] * cs - ko * sn);
  }
  float sq = 0.f, sk = 0.f;
#pragma unroll
  for (int e = 0; e < 16; ++e) { sq += qr[e] * qr[e]; sk += kr[e] * kr[e]; }
  sq += __shfl_xor(sq, 1, 64); sq += __shfl_xor(sq, 2, 64);
  sk += __shfl_xor(sk, 1, 64); sk += __shfl_xor(sk, 2, 64);
  if (h >= 10) {
    const float rq = 1.0f / fmaxf(sqrtf(sq), 1e-12f);
    const float rk = 1.0f / fmaxf(sqrtf(sk), 1e-12f);
#pragma unroll
    for (int e = 0; e < 16; ++e) { qr[e] *= rq; kr[e] *= rk; }
  }
  if (seg == 0) {
    const int idx = b * 32768 + h * 2048 + t;
    float oq = sq, ok = sk;
    if (h >= 6 && h < 10) {
      const float invc = 1.0f / curvg[h - 6];
      oq = sqrtf(invc + sq);
      ok = sqrtf(invc + sk);
    }
    qq[idx] = oq;
    kk[idx] = ok;
  }
  const int st = seg >> 1;
  const int quadA = (seg * 2) & 3, quadB = (seg * 2 + 1) & 3;
  {
    unsigned int wh[8], wl[8];
#pragma unroll
    for (int p = 0; p < 8; ++p) {
      unsigned short h0 = f2bf(qr[2*p]), h1 = f2bf(qr[2*p+1]);
      unsigned short l0 = f2bf(qr[2*p] - bf2f(h0)), l1 = f2bf(qr[2*p+1] - bf2f(h1));
      wh[p] = (unsigned)h0 | ((unsigned)h1 << 16);
      wl[p] = (unsigned)l0 | ((unsigned)l1 << 16);
    }
    const int qi = (t >> 4) & 1, c15q = t & 15;
    unsigned short* qs = Q2 + ((size_t)bh * 64 + (t >> 5)) * 4096;
    const int fh = ((qi * 2 + st) * 2 + 0) * 512, fl = fh + 512;
    *(uint4*)(qs + fh + quadA * 128 + c15q * 8) = uint4{wh[0], wh[1], wh[2], wh[3]};
    *(uint4*)(qs + fh + quadB * 128 + c15q * 8) = uint4{wh[4], wh[5], wh[6], wh[7]};
    *(uint4*)(qs + fl + quadA * 128 + c15q * 8) = uint4{wl[0], wl[1], wl[2], wl[3]};
    *(uint4*)(qs + fl + quadB * 128 + c15q * 8) = uint4{wl[4], wl[5], wl[6], wl[7]};
#pragma unroll
    for (int p = 0; p < 8; ++p) {
      unsigned short h0 = f2bf(kr[2*p]), h1 = f2bf(kr[2*p+1]);
      unsigned short l0 = f2bf(kr[2*p] - bf2f(h0)), l1 = f2bf(kr[2*p+1] - bf2f(h1));
      wh[p] = (unsigned)h0 | ((unsigned)h1 << 16);
      wl[p] = (unsigned)l0 | ((unsigned)l1 << 16);
    }
    const int kj = (tr >> 4) & 3, c15k = tr & 15;
    unsigned short* ks = K2 + ((size_t)bh * 32 + ttile) * 8192;
    const int gh = ((st * 4 + kj) * 2 + 0) * 512, gl = gh + 512;
    *(uint4*)(ks + gh + quadA * 128 + c15k * 8) = uint4{wh[0], wh[1], wh[2], wh[3]};
    *(uint4*)(ks + gh + quadB * 128 + c15k * 8) = uint4{wh[4], wh[5], wh[6], wh[7]};
    *(uint4*)(ks + gl + quadA * 128 + c15k * 8) = uint4{wl[0], wl[1], wl[2], wl[3]};
    *(uint4*)(ks + gl + quadB * 128 + c15k * 8) = uint4{wl[4], wl[5], wl[6], wl[7]};
  }
#pragma unroll
  for (int e = 0; e < 16; ++e) Vl[(seg * 16 + e) * 66 + tr] = f2bf(vv[e]);
  __syncthreads();
  {
    const int d = tid >> 2, tch = (tid & 3) * 16;
    unsigned int wv2[8];
#pragma unroll
    for (int p = 0; p < 8; ++p) {
      const unsigned short a0 = Vl[d * 66 + tch + 2*p];
      const unsigned short a1 = Vl[d * 66 + tch + 2*p + 1];
      wv2[p] = (unsigned)a0 | ((unsigned)a1 << 16);
    }
    const int dj = d >> 4, c15v = d & 15;
    const int ks2 = tch >> 5;
    const int qvA = (tch >> 3) & 3, qvB = ((tch >> 3) + 1) & 3;
    unsigned short* vs = V2 + ((size_t)bh * 32 + ttile) * 4096 + (ks2 * 4 + dj) * 512;
    *(uint4*)(vs + qvA * 128 + c15v * 8) = uint4{wv2[0], wv2[1], wv2[2], wv2[3]};
    *(uint4*)(vs + qvB * 128 + c15v * 8) = uint4{wv2[4], wv2[5], wv2[6], wv2[7]};
  }
}

// Split-K barrier-free MFMA flash attention. 1 wave/block, 5120 blocks.
// 2-product scores ((qh+ql)*kh). Per-wave LDS double-buffer (K 8KB + V 8KB per buf)
// filled by global_load_lds; explicit vmcnt(0) one iteration after issue.
__global__ __launch_bounds__(64) void attn_part(
    const unsigned short* __restrict__ Q2, const unsigned short* __restrict__ K2,
    const unsigned short* __restrict__ V2, const float* __restrict__ tqq,
    const float* __restrict__ tkk, const float* __restrict__ curvg,
    float* __restrict__ part) {
  alignas(16) __shared__ char KV[2][16384];            // [buf][K 8KB | V 8KB]
  alignas(16) __shared__ unsigned short Pl[32 * 64];   // 4KB P tile
  const int lane = threadIdx.x;
  const int quad = lane >> 4, c15 = lane & 15;
  const int z = blockIdx.x, bh = z & 31;
  const int u = 159 - (z >> 5);          // slot-in-bh, big (qw,ch) first
  int qw, ch;
  if (u < 16)      { qw = u; ch = 0; }
  else if (u < 48) { qw = 16 + ((u - 16) >> 1); ch = (u - 16) & 1; }
  else if (u < 96) { const int s2 = u - 48; const int q3 = s2 / 3; qw = 32 + q3; ch = s2 - 3 * q3; }
  else             { const int s2 = u - 96; qw = 48 + (s2 >> 2); ch = s2 & 3; }
  const int h = bh & 15;
  const int geom = (h < 6) ? 0 : ((h < 10) ? 1 : 2);
  const int qrow0 = qw * 32;
  const f32x4 zero4 = {0.f, 0.f, 0.f, 0.f};

  // Q fragments: lane-linear loads (hi and lo halves; scores use both vs K-hi)
  const unsigned short* qbase = Q2 + ((size_t)bh * 64 + qw) * 4096;
  bf16x8 qh[2][2], ql[2][2];
#pragma unroll
  for (int qi = 0; qi < 2; ++qi)
#pragma unroll
    for (int st = 0; st < 2; ++st) {
      const int f = ((qi * 2 + st) * 2) * 512 + lane * 8;
      qh[qi][st] = *(const bf16x8*)(qbase + f);
      ql[qi][st] = *(const bf16x8*)(qbase + f + 512);
    }

  float curv = 1.f, sic = 1.f, sscale = 0.125f, Moff = 16.0f;
  f32x4 tq4[2] = {zero4, zero4};
  if (geom == 1) {
    curv = curvg[h - 6];
    sic = sqrtf(1.0f / curv);
    Moff = 4.0f;
#pragma unroll
    for (int qi = 0; qi < 2; ++qi)
      tq4[qi] = *(const f32x4*)(tqq + bh * 2048 + qrow0 + qi * 16 + quad * 4);
  } else if (geom == 2) {
    sscale = 8.0f;
    Moff = 8.0f;
  }
  // exp(s*sscale - Moff) = exp2(s*sA - mB)
  const float sA = sscale * 1.4426950408889634f;
  const float mB = Moff * 1.4426950408889634f;

  const __bf16 one_b = (__bf16)1.0f;
  const bf16x8 ones = {one_b, one_b, one_b, one_b, one_b, one_b, one_b, one_b};

  f32x4 o[2][4];
  f32x4 ol[2] = {zero4, zero4};
#pragma unroll
  for (int qi = 0; qi < 2; ++qi)
#pragma unroll
    for (int dj = 0; dj < 4; ++dj) o[qi][dj] = zero4;

  const int nkt = (qw >> 1) + 1;
  const int ktB = ch * 8;
  const int ktE = (ktB + 8 < nkt) ? (ktB + 8) : nkt;

  const unsigned short* Kbh = K2 + (size_t)bh * 32 * 8192;
  const unsigned short* Vbh = V2 + (size_t)bh * 32 * 4096;

  // stage ktile kt into buffer buf: K hi frags (even frag slots) + V frags.
  auto stage = [&](int buf, int kt) {
    const unsigned short* kbase = Kbh + (size_t)kt * 8192;   // hi frag f at f*1024
    const unsigned short* vbase = Vbh + (size_t)kt * 4096;
    char* kd = KV[buf];
    char* vd = KV[buf] + 8192;
#pragma unroll
    for (int f = 0; f < 8; ++f)
      async_copy16(kbase + f * 1024 + lane * 8, kd + f * 1024 + lane * 16);
#pragma unroll
    for (int f = 0; f < 8; ++f)
      async_copy16(vbase + f * 512 + lane * 8, vd + f * 1024 + lane * 16);
  };

  stage(0, ktB);
  for (int kt = ktB; kt < ktE; ++kt) {
    const int buf = (kt - ktB) & 1;
    wait_vm0();                      // current buffer's copies (issued last iter) done
    if (kt + 1 < ktE) stage(buf ^ 1, kt + 1);

    const char* Kbuf = KV[buf];
    const char* Vbuf = KV[buf] + 8192;
    const int kb = kt * 64;

    // ---- S = Q·K^T, 2-product: (qh+ql)·kh
    f32x4 s[2][4];
#pragma unroll
    for (int qi = 0; qi < 2; ++qi)
#pragma unroll
      for (int kj = 0; kj < 4; ++kj) s[qi][kj] = zero4;
#pragma unroll
    for (int st = 0; st < 2; ++st) {
#pragma unroll
      for (int kj = 0; kj < 4; ++kj) {
        const bf16x8 bhf = *(const bf16x8*)(Kbuf + (st * 4 + kj) * 1024 + lane * 16);
#pragma unroll
        for (int qi = 0; qi < 2; ++qi) {
          s[qi][kj] = __builtin_amdgcn_mfma_f32_16x16x32_bf16(qh[qi][st], bhf, s[qi][kj], 0, 0, 0);
          s[qi][kj] = __builtin_amdgcn_mfma_f32_16x16x32_bf16(ql[qi][st], bhf, s[qi][kj], 0, 0, 0);
        }
      }
    }

    // ---- p = exp(score - M_static); mask only the straddling last ktile
    const bool needmask = (kt == nkt - 1);
#pragma unroll
    for (int qi = 0; qi < 2; ++qi) {
      const int qbaserow = qrow0 + qi * 16 + quad * 4;
#pragma unroll
      for (int kj = 0; kj < 4; ++kj) {
        const int skey = kj * 16 + c15;
        const int key = kb + skey;
        const f32x4 d4 = s[qi][kj];
        f32x4 p;
        if (geom == 1) {
          const float tk = tkk[bh * 2048 + key];
#pragma unroll
          for (int r = 0; r < 4; ++r) {
            const float a = fmaxf(curv * (tq4[qi][r] * tk - d4[r]), 1.0f + 1e-7f);
            const float dis = sic * __logf(a + sqrtf(a * a - 1.0f));
            p[r] = __expf(__builtin_amdgcn_rcpf(1e-6f + dis) - Moff);
          }
        } else {
#pragma unroll
          for (int r = 0; r < 4; ++r) p[r] = exp2f(d4[r] * sA - mB);
        }
        if (needmask) {
#pragma unroll
          for (int r = 0; r < 4; ++r)
            if (key > qbaserow + r) p[r] = 0.0f;
        }
#pragma unroll
        for (int r = 0; r < 4; ++r) {
          union { float f; unsigned u2; } pv; pv.f = p[r];
          const int row = qi * 16 + quad * 4 + r;
          const int g = (skey >> 3) ^ (row & 7);
          Pl[row * 64 + g * 8 + (skey & 7)] = (unsigned short)(pv.u2 >> 16);
        }
      }
    }

    // ---- PV: O += P·V^T ; l += P·1 ; V frags from staged LDS
#pragma unroll
    for (int ks2 = 0; ks2 < 2; ++ks2) {
      bf16x8 av[2];
#pragma unroll
      for (int qi = 0; qi < 2; ++qi) {
        const int m = qi * 16 + c15;
        const int g = (ks2 * 4 + quad) ^ (m & 7);
        av[qi] = *(const bf16x8*)(Pl + m * 64 + g * 8);
        ol[qi] = __builtin_amdgcn_mfma_f32_16x16x32_bf16(av[qi], ones, ol[qi], 0, 0, 0);
      }
#pragma unroll
      for (int dj = 0; dj < 4; ++dj) {
        const bf16x8 bv = *(const bf16x8*)(Vbuf + (ks2 * 4 + dj) * 1024 + lane * 16);
#pragma unroll
        for (int qi = 0; qi < 2; ++qi)
          o[qi][dj] = __builtin_amdgcn_mfma_f32_16x16x32_bf16(av[qi], bv, o[qi][dj], 0, 0, 0);
      }
    }
  }

  // ---- partial write: slot = bh*160 + u, stride 2112 f32
  float* slot = part + (size_t)(bh * 160 + u) * 2112;
#pragma unroll
  for (int qi = 0; qi < 2; ++qi)
#pragma unroll
    for (int dj = 0; dj < 4; ++dj)
      *(f32x4*)(slot + (qi * 4 + dj) * 256 + lane * 4) = o[qi][dj];
  if (c15 == 0) {
#pragma unroll
    for (int qi = 0; qi < 2; ++qi)
      *(f32x4*)(slot + 2048 + qi * 16 + quad * 4) = ol[qi];
  }
}

// Sum chunk partials, divide, LDS-transpose, write A'y [hi|lo|hi] with 16B stores.
__global__ __launch_bounds__(64) void attn_reduce(
    const float* __restrict__ part, unsigned short* __restrict__ Ay) {
  __shared__ float Ol[32 * 65];
  const int lane = threadIdx.x;
  const int quad = lane >> 4, c15 = lane & 15;
  const int z = blockIdx.x, bh = z & 31, qw = 63 - (z >> 5);
  const int b = bh >> 4, h = bh & 15;
  const int G = qw >> 4;
  const int base = qw + 8 * G * (G - 1) + (qw & 15) * G;
  const float* slot0 = part + (size_t)(bh * 160 + base) * 2112;

  const f32x4 zero4 = {0.f, 0.f, 0.f, 0.f};
  f32x4 o[8];
  f32x4 l4[2] = {zero4, zero4};
#pragma unroll
  for (int i = 0; i < 8; ++i) o[i] = zero4;
  for (int chv = 0; chv <= G; ++chv) {
    const float* sl = slot0 + chv * 2112;
#pragma unroll
    for (int i = 0; i < 8; ++i) o[i] += *(const f32x4*)(sl + i * 256 + lane * 4);
#pragma unroll
    for (int qi = 0; qi < 2; ++qi)
      l4[qi] += *(const f32x4*)(sl + 2048 + qi * 16 + quad * 4);
  }
#pragma unroll
  for (int qi = 0; qi < 2; ++qi) {
    f32x4 invl;
#pragma unroll
    for (int r = 0; r < 4; ++r) invl[r] = __builtin_amdgcn_rcpf(l4[qi][r]);
#pragma unroll
    for (int dj = 0; dj < 4; ++dj) {
      const f32x4 val = o[qi * 4 + dj] * invl;
#pragma unroll
      for (int r = 0; r < 4; ++r)
        Ol[(qi * 16 + quad * 4 + r) * 65 + dj * 16 + c15] = val[r];
    }
  }
  __syncthreads();   // single wave, but ensure LDS visibility across lanes
  const int row = lane >> 1, half = lane & 1;
  const float* rp = Ol + row * 65 + half * 32;
  unsigned int uh[16], ul2[16];
#pragma unroll
  for (int p = 0; p < 16; ++p) {
    const float v0 = rp[2 * p], v1 = rp[2 * p + 1];
    const unsigned short h0 = f2bf(v0), h1 = f2bf(v1);
    const unsigned short g0 = f2bf(v0 - bf2f(h0)), g1 = f2bf(v1 - bf2f(h1));
    uh[p] = (unsigned)h0 | ((unsigned)h1 << 16);
    ul2[p] = (unsigned)g0 | ((unsigned)g1 << 16);
  }
  unsigned short* yp = Ay + ((size_t)(b * 2048 + qw * 32 + row)) * 3072 + h * 64 + half * 32;
#pragma unroll
  for (int c = 0; c < 4; ++c) {
    const uint4 vh = uint4{uh[4*c], uh[4*c+1], uh[4*c+2], uh[4*c+3]};
    const uint4 vl = uint4{ul2[4*c], ul2[4*c+1], ul2[4*c+2], ul2[4*c+3]};
    *(uint4*)(yp + 8 * c)        = vh;   // hi
    *(uint4*)(yp + 1024 + 8 * c) = vl;   // lo
    *(uint4*)(yp + 2048 + 8 * c) = vh;   // hi
  }
}

extern "C" void kernel_launch(void* const* d_in, const int* in_sizes, int n_in,
                              void* d_out, int out_size, void* d_ws, size_t ws_size,
                              hipStream_t stream) {
  const float* x      = (const float*)d_in[0];
  const float* qkv_w  = (const float*)d_in[1];
  const float* proj_w = (const float*)d_in[2];
  const float* proj_b = (const float*)d_in[3];
  const float* curvature = (const float*)d_in[4];
  float* out = (float*)d_out;

  char* ws = (char*)d_ws;
  unsigned short* AX   = (unsigned short*)ws;                     // phase1
  unsigned short* BW   = (unsigned short*)(ws + 25165824);
  float*          QKVF = (float*)(ws + 44040192);
  unsigned short* Q2   = (unsigned short*)ws;                     // post-prep
  unsigned short* K2   = (unsigned short*)(ws + 16777216);
  unsigned short* V2   = (unsigned short*)(ws + 33554432);
  unsigned short* BPW  = (unsigned short*)(ws + 44040192);
  float*          PART = (float*)(ws + 50331648);                 // 43,253,760 B
  unsigned short* AY   = (unsigned short*)ws;                     // post-attn
  float*          QQ   = (float*)(ws + 94371840);
  float*          KK   = (float*)(ws + 94633984);

  split3<0><<<4096, 256, 0, stream>>>(x, AX);
  split3<1><<<3072, 256, 0, stream>>>(qkv_w, BW);

  gemm_bt<0><<<dim3(24, 32), 256, 0, stream>>>(AX, BW, QKVF, nullptr, 3072, 3072);

  prep<<<1024, 256, 0, stream>>>(QKVF, Q2, K2, V2, QQ, KK, curvature);

  split3<1><<<1024, 256, 0, stream>>>(proj_w, BPW);

  attn_part<<<5120, 64, 0, stream>>>(Q2, K2, V2, QQ, KK, curvature, PART);

  attn_reduce<<<2048, 64, 0, stream>>>(PART, AY);

  gemm_bt<1><<<dim3(8, 32), 256, 0, stream>>>(AY, BPW, out, proj_b, 1024, 3072);
}

// Round 12
// 360.423 us; speedup vs baseline: 1.1716x; 1.1716x over previous
//
#include <hip/hip_runtime.h>
#include <stdint.h>
#include <math.h>

// MultiGeometryAttention — f32 in/out. B=2 T=2048 C=1024 H=16 HD=64.
// heads 0-5 sdpa(0.125) | 6-9 hyperbolic(curvature) | 10-15 cos-normalized sdpa(8).
// Split-bf16 (no fp32 MFMA): x*W via A'=[hi|lo|hi],B'=[hi|hi|lo] K'=3K GEMM.
// Attention: static-max softmax, split-K partials, fragment-linear tiles.
// R12 (= R8 body, two deltas):
//  (a) 2-product scores (qh+ql)·kh [proven safe in R11 — absmax identical]:
//      K loads 16->8 per ktile, S-MFMA 48->32. VGPR stays ~108, LDS 4KB.
//  (b) bh-MAJOR block order (bh = z/160): consecutive blocks share a head, so only
//      ~4-8 heads are active chip-wide at any instant (~3-6MB) vs R8's z&31
//      interleave (24MB) -> K/V fragment loads hit hot L2 (~250cy) instead of
//      thrashing to L3 (~900cy). Attacks the measured L~10k cyc/wave-ktile.
// WS (proven peak 94,896,128 B): layout identical to R8/R10.

typedef __bf16 bf16x8 __attribute__((ext_vector_type(8)));
typedef float f32x4 __attribute__((ext_vector_type(4)));

static __device__ __forceinline__ float bf2f(unsigned short u) {
  union { unsigned int i; float f; } v; v.i = ((unsigned int)u) << 16; return v.f;
}
static __device__ __forceinline__ unsigned short f2bf(float f) {
  union { float f; unsigned int i; } v; v.f = f;
  unsigned int x = v.i;
  x += 0x7fffu + ((x >> 16) & 1u);   // RNE
  return (unsigned short)(x >> 16);
}

// direct global->LDS async copy, 16B/lane (gemm staging only).
static __device__ __forceinline__ void async_copy16(const void* gsrc, void* ldst) {
  auto* lp = reinterpret_cast<__attribute__((address_space(3))) unsigned int*>(
      reinterpret_cast<uintptr_t>(ldst));
  auto* gp = reinterpret_cast<const __attribute__((address_space(1))) unsigned int*>(
      reinterpret_cast<uintptr_t>(gsrc));
  __builtin_amdgcn_global_load_lds(gp, lp, 16, 0, 0);
}

// f32 [rows][1024] -> split bf16 [rows][3072]. PAT=0 (A): [hi|lo|hi]; PAT=1 (B): [hi|hi|lo].
template <int PAT>
__global__ __launch_bounds__(256) void split3(const float* __restrict__ in,
                                              unsigned short* __restrict__ out) {
  const int row = blockIdx.x;
  const int kq = threadIdx.x * 4;
  const f32x4 x = *(const f32x4*)(in + (size_t)row * 1024 + kq);
  unsigned short hi[4], lo[4];
#pragma unroll
  for (int i = 0; i < 4; ++i) {
    hi[i] = f2bf(x[i]);
    lo[i] = f2bf(x[i] - bf2f(hi[i]));   // exact residual in f32
  }
  uint2 uh, ul;
  uh.x = (unsigned)hi[0] | ((unsigned)hi[1] << 16);
  uh.y = (unsigned)hi[2] | ((unsigned)hi[3] << 16);
  ul.x = (unsigned)lo[0] | ((unsigned)lo[1] << 16);
  ul.y = (unsigned)lo[2] | ((unsigned)lo[3] << 16);
  unsigned short* op = out + (size_t)row * 3072 + kq;
  *(uint2*)(op)        = uh;
  *(uint2*)(op + 1024) = PAT ? uh : ul;
  *(uint2*)(op + 2048) = PAT ? ul : uh;
}

// C[m][n] = sum_k A[m][k]*B[n][k] (+bias[n]) -> f32. 128x128 tile, BK=64, 4 waves,
// 16x16x32 bf16 MFMA, XOR-swizzled LDS (verified).
template <int HASBIAS>
__global__ __launch_bounds__(256) void gemm_bt(
    const unsigned short* __restrict__ A, const unsigned short* __restrict__ Bm,
    float* __restrict__ C, const float* __restrict__ bias, int N_, int K_) {
  alignas(16) __shared__ unsigned short smA[128 * 64];
  alignas(16) __shared__ unsigned short smB[128 * 64];
  const int tid = threadIdx.x;
  const int lane = tid & 63;
  const int wv = tid >> 6;
  const int wm = wv >> 1, wn = wv & 1;
  const long m0 = (long)blockIdx.y * 128, n0 = (long)blockIdx.x * 128;

  const f32x4 zero4 = {0.f, 0.f, 0.f, 0.f};
  f32x4 acc[4][4];
#pragma unroll
  for (int i = 0; i < 4; ++i)
#pragma unroll
    for (int j = 0; j < 4; ++j) acc[i][j] = zero4;

  int mrow[4], gg[4];
#pragma unroll
  for (int w = 0; w < 4; ++w) {
    int c = w * 256 + tid;
    mrow[w] = c >> 3;
    gg[w] = (c & 7) ^ ((c >> 3) & 7);
  }

  const int kTiles = K_ >> 6;
  for (int kt = 0; kt < kTiles; ++kt) {
    if (kt) __syncthreads();
    const int kb = kt << 6;
#pragma unroll
    for (int w = 0; w < 4; ++w) {
      const int c = w * 256 + tid;
      async_copy16(A + (size_t)(m0 + mrow[w]) * K_ + kb + gg[w] * 8,
                   (char*)smA + c * 16);
      async_copy16(Bm + (size_t)(n0 + mrow[w]) * K_ + kb + gg[w] * 8,
                   (char*)smB + c * 16);
    }
    __syncthreads();
#pragma unroll
    for (int ks = 0; ks < 2; ++ks) {
      bf16x8 af[4], bg[4];
#pragma unroll
      for (int i = 0; i < 4; ++i) {
        const int ra = wm * 64 + i * 16 + (lane & 15);
        const int ga = (ks * 4 + (lane >> 4)) ^ (ra & 7);
        af[i] = *(const bf16x8*)((const char*)smA + ra * 128 + ga * 16);
        const int rb = wn * 64 + i * 16 + (lane & 15);
        const int gb2 = (ks * 4 + (lane >> 4)) ^ (rb & 7);
        bg[i] = *(const bf16x8*)((const char*)smB + rb * 128 + gb2 * 16);
      }
#pragma unroll
      for (int i = 0; i < 4; ++i)
#pragma unroll
        for (int j = 0; j < 4; ++j)
          acc[i][j] = __builtin_amdgcn_mfma_f32_16x16x32_bf16(af[i], bg[j], acc[i][j], 0, 0, 0);
    }
  }

  const int r0 = wm * 64 + (lane >> 4) * 4;
  const int c0 = wn * 64 + (lane & 15);
#pragma unroll
  for (int j = 0; j < 4; ++j) {
    const long col = n0 + c0 + j * 16;
    float bv = 0.f;
    if (HASBIAS) bv = bias[col];
#pragma unroll
    for (int i = 0; i < 4; ++i) {
#pragma unroll
      for (int r = 0; r < 4; ++r) {
        const long row = m0 + r0 + i * 16 + r;
        C[row * N_ + col] = acc[i][j][r] + bv;
      }
    }
  }
}

// prep: rotary q,k; norms; normalize h>=10; tq/tk for hyperbolic; emit FRAGMENT-LINEAR
// tiles (element (frag,quad,c15,j) at frag*512 + quad*128 + c15*8 + j).
__global__ __launch_bounds__(256) void prep(
    const float* __restrict__ qkvf, unsigned short* __restrict__ Q2,
    unsigned short* __restrict__ K2, unsigned short* __restrict__ V2,
    float* __restrict__ qq, float* __restrict__ kk, const float* __restrict__ curvg) {
  __shared__ unsigned short Vl[64 * 66];
  const int tid = threadIdx.x;
  const int zz = blockIdx.x;
  const int ttile = zz & 31, bh = zz >> 5;
  const int b = bh >> 4, h = bh & 15;
  const int t0 = ttile * 64;
  const int tr = tid >> 2, seg = tid & 3;
  const int t = t0 + tr;
  const float* src = qkvf + ((size_t)(b * 2048 + t)) * 3072 + h * 64 + seg * 16;

  float qv[16], kv[16], vv[16];
#pragma unroll
  for (int c = 0; c < 4; ++c) {
    const f32x4 a  = *(const f32x4*)(src + c * 4);
    const f32x4 bb = *(const f32x4*)(src + 1024 + c * 4);
    const f32x4 cc = *(const f32x4*)(src + 2048 + c * 4);
#pragma unroll
    for (int e = 0; e < 4; ++e) { qv[c*4+e] = a[e]; kv[c*4+e] = bb[e]; vv[c*4+e] = cc[e]; }
  }
  float qr[16], kr[16];
#pragma unroll
  for (int e = 0; e < 16; ++e) {
    const int d = seg * 16 + e;
    const int i = d & 31;
    const float invf = exp2f(-0.41524101186109286f * (float)i);  // 10000^(-i/32)
    float sn, cs;
    sincosf((float)t * invf, &sn, &cs);
    const float qo = __shfl_xor(qv[e], 2, 64);
    const float ko = __shfl_xor(kv[e], 2, 64);
    qr[e] = (d < 32) ? (qv[e] * cs + qo * sn) : (qv[e] * cs - qo * sn);
    kr[e] = (d < 32) ? (kv[e] * cs + ko * sn) : (kv[e] * cs - ko * sn);
  }
  float sq = 0.f, sk = 0.f;
#pragma unroll
  for (int e = 0; e < 16; ++e) { sq += qr[e] * qr[e]; sk += kr[e] * kr[e]; }
  sq += __shfl_xor(sq, 1, 64); sq += __shfl_xor(sq, 2, 64);
  sk += __shfl_xor(sk, 1, 64); sk += __shfl_xor(sk, 2, 64);
  if (h >= 10) {
    const float rq = 1.0f / fmaxf(sqrtf(sq), 1e-12f);
    const float rk = 1.0f / fmaxf(sqrtf(sk), 1e-12f);
#pragma unroll
    for (int e = 0; e < 16; ++e) { qr[e] *= rq; kr[e] *= rk; }
  }
  if (seg == 0) {
    const int idx = b * 32768 + h * 2048 + t;
    float oq = sq, ok = sk;
    if (h >= 6 && h < 10) {
      const float invc = 1.0f / curvg[h - 6];
      oq = sqrtf(invc + sq);
      ok = sqrtf(invc + sk);
    }
    qq[idx] = oq;
    kk[idx] = ok;
  }
  const int st = seg >> 1;
  const int quadA = (seg * 2) & 3, quadB = (seg * 2 + 1) & 3;
  {
    unsigned int wh[8], wl[8];
#pragma unroll
    for (int p = 0; p < 8; ++p) {
      unsigned short h0 = f2bf(qr[2*p]), h1 = f2bf(qr[2*p+1]);
      unsigned short l0 = f2bf(qr[2*p] - bf2f(h0)), l1 = f2bf(qr[2*p+1] - bf2f(h1));
      wh[p] = (unsigned)h0 | ((unsigned)h1 << 16);
      wl[p] = (unsigned)l0 | ((unsigned)l1 << 16);
    }
    const int qi = (t >> 4) & 1, c15q = t & 15;
    unsigned short* qs = Q2 + ((size_t)bh * 64 + (t >> 5)) * 4096;
    const int fh = ((qi * 2 + st) * 2 + 0) * 512, fl = fh + 512;
    *(uint4*)(qs + fh + quadA * 128 + c15q * 8) = uint4{wh[0], wh[1], wh[2], wh[3]};
    *(uint4*)(qs + fh + quadB * 128 + c15q * 8) = uint4{wh[4], wh[5], wh[6], wh[7]};
    *(uint4*)(qs + fl + quadA * 128 + c15q * 8) = uint4{wl[0], wl[1], wl[2], wl[3]};
    *(uint4*)(qs + fl + quadB * 128 + c15q * 8) = uint4{wl[4], wl[5], wl[6], wl[7]};
#pragma unroll
    for (int p = 0; p < 8; ++p) {
      unsigned short h0 = f2bf(kr[2*p]), h1 = f2bf(kr[2*p+1]);
      unsigned short l0 = f2bf(kr[2*p] - bf2f(h0)), l1 = f2bf(kr[2*p+1] - bf2f(h1));
      wh[p] = (unsigned)h0 | ((unsigned)h1 << 16);
      wl[p] = (unsigned)l0 | ((unsigned)l1 << 16);
    }
    const int kj = (tr >> 4) & 3, c15k = tr & 15;
    unsigned short* ks = K2 + ((size_t)bh * 32 + ttile) * 8192;
    const int gh = ((st * 4 + kj) * 2 + 0) * 512, gl = gh + 512;
    *(uint4*)(ks + gh + quadA * 128 + c15k * 8) = uint4{wh[0], wh[1], wh[2], wh[3]};
    *(uint4*)(ks + gh + quadB * 128 + c15k * 8) = uint4{wh[4], wh[5], wh[6], wh[7]};
    *(uint4*)(ks + gl + quadA * 128 + c15k * 8) = uint4{wl[0], wl[1], wl[2], wl[3]};
    *(uint4*)(ks + gl + quadB * 128 + c15k * 8) = uint4{wl[4], wl[5], wl[6], wl[7]};
  }
#pragma unroll
  for (int e = 0; e < 16; ++e) Vl[(seg * 16 + e) * 66 + tr] = f2bf(vv[e]);
  __syncthreads();
  {
    const int d = tid >> 2, tch = (tid & 3) * 16;
    unsigned int wv2[8];
#pragma unroll
    for (int p = 0; p < 8; ++p) {
      const unsigned short a0 = Vl[d * 66 + tch + 2*p];
      const unsigned short a1 = Vl[d * 66 + tch + 2*p + 1];
      wv2[p] = (unsigned)a0 | ((unsigned)a1 << 16);
    }
    const int dj = d >> 4, c15v = d & 15;
    const int ks2 = tch >> 5;
    const int qvA = (tch >> 3) & 3, qvB = ((tch >> 3) + 1) & 3;
    unsigned short* vs = V2 + ((size_t)bh * 32 + ttile) * 4096 + (ks2 * 4 + dj) * 512;
    *(uint4*)(vs + qvA * 128 + c15v * 8) = uint4{wv2[0], wv2[1], wv2[2], wv2[3]};
    *(uint4*)(vs + qvB * 128 + c15v * 8) = uint4{wv2[4], wv2[5], wv2[6], wv2[7]};
  }
}

// Split-K barrier-free MFMA flash attention (R8 body, 2-product scores).
// 1 wave/block, 5120 blocks, bh-MAJOR order: bh = z/160 so consecutive blocks
// share a head -> hot-L2 K/V fragment loads.
__global__ __launch_bounds__(64) void attn_part(
    const unsigned short* __restrict__ Q2, const unsigned short* __restrict__ K2,
    const unsigned short* __restrict__ V2, const float* __restrict__ tqq,
    const float* __restrict__ tkk, const float* __restrict__ curvg,
    float* __restrict__ part) {
  alignas(16) __shared__ unsigned short Pl[32 * 64];   // 4KB wave-private P tile
  const int lane = threadIdx.x;
  const int quad = lane >> 4, c15 = lane & 15;
  const int z = blockIdx.x;
  const int bh = z / 160;                // bh-major: same head in consecutive blocks
  const int uu = z - bh * 160;
  const int u = 159 - uu;                // big (qw,ch) first within the head
  int qw, ch;
  if (u < 16)      { qw = u; ch = 0; }
  else if (u < 48) { qw = 16 + ((u - 16) >> 1); ch = (u - 16) & 1; }
  else if (u < 96) { const int s2 = u - 48; const int q3 = s2 / 3; qw = 32 + q3; ch = s2 - 3 * q3; }
  else             { const int s2 = u - 96; qw = 48 + (s2 >> 2); ch = s2 & 3; }
  const int h = bh & 15;
  const int geom = (h < 6) ? 0 : ((h < 10) ? 1 : 2);
  const int qrow0 = qw * 32;
  const f32x4 zero4 = {0.f, 0.f, 0.f, 0.f};

  // Q fragments: lane-linear loads (hi+lo; 2-product scores use both vs K-hi)
  const unsigned short* qbase = Q2 + ((size_t)bh * 64 + qw) * 4096;
  bf16x8 qh[2][2], ql[2][2];
#pragma unroll
  for (int qi = 0; qi < 2; ++qi)
#pragma unroll
    for (int st = 0; st < 2; ++st) {
      const int f = ((qi * 2 + st) * 2) * 512 + lane * 8;
      qh[qi][st] = *(const bf16x8*)(qbase + f);
      ql[qi][st] = *(const bf16x8*)(qbase + f + 512);
    }

  float curv = 1.f, sic = 1.f, sscale = 0.125f, Moff = 16.0f;
  f32x4 tq4[2] = {zero4, zero4};
  if (geom == 1) {
    curv = curvg[h - 6];
    sic = sqrtf(1.0f / curv);
    Moff = 4.0f;
#pragma unroll
    for (int qi = 0; qi < 2; ++qi)
      tq4[qi] = *(const f32x4*)(tqq + bh * 2048 + qrow0 + qi * 16 + quad * 4);
  } else if (geom == 2) {
    sscale = 8.0f;
    Moff = 8.0f;
  }

  const __bf16 one_b = (__bf16)1.0f;
  const bf16x8 ones = {one_b, one_b, one_b, one_b, one_b, one_b, one_b, one_b};

  f32x4 o[2][4];
  f32x4 ol[2] = {zero4, zero4};
#pragma unroll
  for (int qi = 0; qi < 2; ++qi)
#pragma unroll
    for (int dj = 0; dj < 4; ++dj) o[qi][dj] = zero4;

  const int nkt = (qw >> 1) + 1;
  const int ktB = ch * 8;
  const int ktE = (ktB + 8 < nkt) ? (ktB + 8) : nkt;
  for (int kt = ktB; kt < ktE; ++kt) {
    const int kb = kt * 64;
    const unsigned short* kbase = K2 + ((size_t)bh * 32 + kt) * 8192;
    const unsigned short* vbase = V2 + ((size_t)bh * 32 + kt) * 4096;

    // ---- S = Q·K^T, 2-product (qh+ql)·kh; K-hi frags only, lane-linear
    f32x4 s[2][4];
#pragma unroll
    for (int qi = 0; qi < 2; ++qi)
#pragma unroll
      for (int kj = 0; kj < 4; ++kj) s[qi][kj] = zero4;
#pragma unroll
    for (int st = 0; st < 2; ++st) {
#pragma unroll
      for (int kj = 0; kj < 4; ++kj) {
        const int f = ((st * 4 + kj) * 2) * 512 + lane * 8;
        const bf16x8 bhf = *(const bf16x8*)(kbase + f);
#pragma unroll
        for (int qi = 0; qi < 2; ++qi) {
          s[qi][kj] = __builtin_amdgcn_mfma_f32_16x16x32_bf16(qh[qi][st], bhf, s[qi][kj], 0, 0, 0);
          s[qi][kj] = __builtin_amdgcn_mfma_f32_16x16x32_bf16(ql[qi][st], bhf, s[qi][kj], 0, 0, 0);
        }
      }
    }

    // ---- p = exp(score - M_static); mask only the straddling last ktile
    const bool needmask = (kt == nkt - 1);
#pragma unroll
    for (int qi = 0; qi < 2; ++qi) {
      const int qbaserow = qrow0 + qi * 16 + quad * 4;
#pragma unroll
      for (int kj = 0; kj < 4; ++kj) {
        const int skey = kj * 16 + c15;
        const int key = kb + skey;
        const f32x4 d4 = s[qi][kj];
        f32x4 p;
        if (geom == 1) {
          const float tk = tkk[bh * 2048 + key];
#pragma unroll
          for (int r = 0; r < 4; ++r) {
            const float a = fmaxf(curv * (tq4[qi][r] * tk - d4[r]), 1.0f + 1e-7f);
            const float dis = sic * __logf(a + sqrtf(a * a - 1.0f));
            p[r] = __expf(__builtin_amdgcn_rcpf(1e-6f + dis) - Moff);
          }
        } else {
#pragma unroll
          for (int r = 0; r < 4; ++r) p[r] = __expf(d4[r] * sscale - Moff);
        }
        if (needmask) {
#pragma unroll
          for (int r = 0; r < 4; ++r)
            if (key > qbaserow + r) p[r] = 0.0f;
        }
#pragma unroll
        for (int r = 0; r < 4; ++r) {
          union { float f; unsigned u2; } pv; pv.f = p[r];
          const int row = qi * 16 + quad * 4 + r;
          const int g = (skey >> 3) ^ (row & 7);
          Pl[row * 64 + g * 8 + (skey & 7)] = (unsigned short)(pv.u2 >> 16);
        }
      }
    }

    // ---- PV: O += P·V^T ; l += P·1 ; V loads lane-linear
#pragma unroll
    for (int ks2 = 0; ks2 < 2; ++ks2) {
      bf16x8 av[2];
#pragma unroll
      for (int qi = 0; qi < 2; ++qi) {
        const int m = qi * 16 + c15;
        const int g = (ks2 * 4 + quad) ^ (m & 7);
        av[qi] = *(const bf16x8*)(Pl + m * 64 + g * 8);
        ol[qi] = __builtin_amdgcn_mfma_f32_16x16x32_bf16(av[qi], ones, ol[qi], 0, 0, 0);
      }
#pragma unroll
      for (int dj = 0; dj < 4; ++dj) {
        const bf16x8 bv = *(const bf16x8*)(vbase + (ks2 * 4 + dj) * 512 + lane * 8);
#pragma unroll
        for (int qi = 0; qi < 2; ++qi)
          o[qi][dj] = __builtin_amdgcn_mfma_f32_16x16x32_bf16(av[qi], bv, o[qi][dj], 0, 0, 0);
      }
    }
  }

  // ---- partial write: slot = bh*160 + u, stride 2112 f32
  float* slot = part + (size_t)(bh * 160 + u) * 2112;
#pragma unroll
  for (int qi = 0; qi < 2; ++qi)
#pragma unroll
    for (int dj = 0; dj < 4; ++dj)
      *(f32x4*)(slot + (qi * 4 + dj) * 256 + lane * 4) = o[qi][dj];
  if (c15 == 0) {
#pragma unroll
    for (int qi = 0; qi < 2; ++qi)
      *(f32x4*)(slot + 2048 + qi * 16 + quad * 4) = ol[qi];
  }
}

// Sum chunk partials, divide, LDS-transpose, write A'y [hi|lo|hi] with 16B stores.
__global__ __launch_bounds__(64) void attn_reduce(
    const float* __restrict__ part, unsigned short* __restrict__ Ay) {
  __shared__ float Ol[32 * 65];
  const int lane = threadIdx.x;
  const int quad = lane >> 4, c15 = lane & 15;
  const int z = blockIdx.x, bh = z & 31, qw = 63 - (z >> 5);
  const int b = bh >> 4, h = bh & 15;
  const int G = qw >> 4;
  const int base = qw + 8 * G * (G - 1) + (qw & 15) * G;
  const float* slot0 = part + (size_t)(bh * 160 + base) * 2112;

  const f32x4 zero4 = {0.f, 0.f, 0.f, 0.f};
  f32x4 o[8];
  f32x4 l4[2] = {zero4, zero4};
#pragma unroll
  for (int i = 0; i < 8; ++i) o[i] = zero4;
  for (int chv = 0; chv <= G; ++chv) {
    const float* sl = slot0 + chv * 2112;
#pragma unroll
    for (int i = 0; i < 8; ++i) o[i] += *(const f32x4*)(sl + i * 256 + lane * 4);
#pragma unroll
    for (int qi = 0; qi < 2; ++qi)
      l4[qi] += *(const f32x4*)(sl + 2048 + qi * 16 + quad * 4);
  }
#pragma unroll
  for (int qi = 0; qi < 2; ++qi) {
    f32x4 invl;
#pragma unroll
    for (int r = 0; r < 4; ++r) invl[r] = __builtin_amdgcn_rcpf(l4[qi][r]);
#pragma unroll
    for (int dj = 0; dj < 4; ++dj) {
      const f32x4 val = o[qi * 4 + dj] * invl;
#pragma unroll
      for (int r = 0; r < 4; ++r)
        Ol[(qi * 16 + quad * 4 + r) * 65 + dj * 16 + c15] = val[r];
    }
  }
  __syncthreads();   // single wave, but ensure LDS visibility across lanes
  const int row = lane >> 1, half = lane & 1;
  const float* rp = Ol + row * 65 + half * 32;
  unsigned int uh[16], ul2[16];
#pragma unroll
  for (int p = 0; p < 16; ++p) {
    const float v0 = rp[2 * p], v1 = rp[2 * p + 1];
    const unsigned short h0 = f2bf(v0), h1 = f2bf(v1);
    const unsigned short g0 = f2bf(v0 - bf2f(h0)), g1 = f2bf(v1 - bf2f(h1));
    uh[p] = (unsigned)h0 | ((unsigned)h1 << 16);
    ul2[p] = (unsigned)g0 | ((unsigned)g1 << 16);
  }
  unsigned short* yp = Ay + ((size_t)(b * 2048 + qw * 32 + row)) * 3072 + h * 64 + half * 32;
#pragma unroll
  for (int c = 0; c < 4; ++c) {
    const uint4 vh = uint4{uh[4*c], uh[4*c+1], uh[4*c+2], uh[4*c+3]};
    const uint4 vl = uint4{ul2[4*c], ul2[4*c+1], ul2[4*c+2], ul2[4*c+3]};
    *(uint4*)(yp + 8 * c)        = vh;   // hi
    *(uint4*)(yp + 1024 + 8 * c) = vl;   // lo
    *(uint4*)(yp + 2048 + 8 * c) = vh;   // hi
  }
}

extern "C" void kernel_launch(void* const* d_in, const int* in_sizes, int n_in,
                              void* d_out, int out_size, void* d_ws, size_t ws_size,
                              hipStream_t stream) {
  const float* x      = (const float*)d_in[0];
  const float* qkv_w  = (const float*)d_in[1];
  const float* proj_w = (const float*)d_in[2];
  const float* proj_b = (const float*)d_in[3];
  const float* curvature = (const float*)d_in[4];
  float* out = (float*)d_out;

  char* ws = (char*)d_ws;
  unsigned short* AX   = (unsigned short*)ws;                     // phase1
  unsigned short* BW   = (unsigned short*)(ws + 25165824);
  float*          QKVF = (float*)(ws + 44040192);
  unsigned short* Q2   = (unsigned short*)ws;                     // post-prep
  unsigned short* K2   = (unsigned short*)(ws + 16777216);
  unsigned short* V2   = (unsigned short*)(ws + 33554432);
  unsigned short* BPW  = (unsigned short*)(ws + 44040192);
  float*          PART = (float*)(ws + 50331648);                 // 43,253,760 B
  unsigned short* AY   = (unsigned short*)ws;                     // post-attn
  float*          QQ   = (float*)(ws + 94371840);
  float*          KK   = (float*)(ws + 94633984);

  split3<0><<<4096, 256, 0, stream>>>(x, AX);
  split3<1><<<3072, 256, 0, stream>>>(qkv_w, BW);

  gemm_bt<0><<<dim3(24, 32), 256, 0, stream>>>(AX, BW, QKVF, nullptr, 3072, 3072);

  prep<<<1024, 256, 0, stream>>>(QKVF, Q2, K2, V2, QQ, KK, curvature);

  split3<1><<<1024, 256, 0, stream>>>(proj_w, BPW);

  attn_part<<<5120, 64, 0, stream>>>(Q2, K2, V2, QQ, KK, curvature, PART);

  attn_reduce<<<2048, 64, 0, stream>>>(PART, AY);

  gemm_bt<1><<<dim3(8, 32), 256, 0, stream>>>(AY, BPW, out, proj_b, 1024, 3072);
}

// Round 13
// 313.673 us; speedup vs baseline: 1.3462x; 1.1490x over previous
//
#include <hip/hip_runtime.h>
#include <stdint.h>
#include <math.h>

// MultiGeometryAttention — f32 in/out. B=2 T=2048 C=1024 H=16 HD=64.
// heads 0-5 sdpa(0.125) | 6-9 hyperbolic(curvature) | 10-15 cos-normalized sdpa(8).
// R13 (on R12's 360us): 2-PRODUCT everywhere. GEMMs: x*W ~= (x_hi+x_lo)*W_hi via
// A'=[hi|lo], B'=[hi|hi], K'=2K (err ~2e-3, inside margin). Attention: 2-product
// scores (R11-proven), K2 stores hi-frags ONLY (8MB). Softmax: fold sscale*log2e
// into q at prep (geom0/2) and DROP Moff — constant cancels in o/l exactly;
// hot path = v_exp + shift + ds_write. geom1 path unchanged. bh-major block order
// (R12's win) kept.
// WS (proven peak 94,896,128 B):
//  phase1: AX[0,16777216) BW[16777216,29360128) | QKVF[33554432,83886080)
//  post-prep: Q2[0,16777216) K2hi[16777216,25165824) V2[25165824,33554432)
//             PART[33554432,76808192) BPW[76808192,81002496)
//  post-attn: AY[0,16777216) | QQ[94371840) KK[94633984)

typedef __bf16 bf16x8 __attribute__((ext_vector_type(8)));
typedef float f32x4 __attribute__((ext_vector_type(4)));

static __device__ __forceinline__ float bf2f(unsigned short u) {
  union { unsigned int i; float f; } v; v.i = ((unsigned int)u) << 16; return v.f;
}
static __device__ __forceinline__ unsigned short f2bf(float f) {
  union { float f; unsigned int i; } v; v.f = f;
  unsigned int x = v.i;
  x += 0x7fffu + ((x >> 16) & 1u);   // RNE
  return (unsigned short)(x >> 16);
}

// direct global->LDS async copy, 16B/lane (gemm staging only).
static __device__ __forceinline__ void async_copy16(const void* gsrc, void* ldst) {
  auto* lp = reinterpret_cast<__attribute__((address_space(3))) unsigned int*>(
      reinterpret_cast<uintptr_t>(ldst));
  auto* gp = reinterpret_cast<const __attribute__((address_space(1))) unsigned int*>(
      reinterpret_cast<uintptr_t>(gsrc));
  __builtin_amdgcn_global_load_lds(gp, lp, 16, 0, 0);
}

// f32 [rows][1024] -> split bf16 [rows][2048]. PAT=0 (A): [hi|lo]; PAT=1 (B): [hi|hi].
template <int PAT>
__global__ __launch_bounds__(256) void split2(const float* __restrict__ in,
                                              unsigned short* __restrict__ out) {
  const int row = blockIdx.x;
  const int kq = threadIdx.x * 4;
  const f32x4 x = *(const f32x4*)(in + (size_t)row * 1024 + kq);
  unsigned short hi[4], lo[4];
#pragma unroll
  for (int i = 0; i < 4; ++i) {
    hi[i] = f2bf(x[i]);
    lo[i] = f2bf(x[i] - bf2f(hi[i]));   // exact residual in f32
  }
  uint2 uh, ul;
  uh.x = (unsigned)hi[0] | ((unsigned)hi[1] << 16);
  uh.y = (unsigned)hi[2] | ((unsigned)hi[3] << 16);
  ul.x = (unsigned)lo[0] | ((unsigned)lo[1] << 16);
  ul.y = (unsigned)lo[2] | ((unsigned)lo[3] << 16);
  unsigned short* op = out + (size_t)row * 2048 + kq;
  *(uint2*)(op)        = uh;
  *(uint2*)(op + 1024) = PAT ? uh : ul;
}

// C[m][n] = sum_k A[m][k]*B[n][k] (+bias[n]) -> f32. 128x128 tile, BK=64, 4 waves,
// 16x16x32 bf16 MFMA, XOR-swizzled LDS (verified).
template <int HASBIAS>
__global__ __launch_bounds__(256) void gemm_bt(
    const unsigned short* __restrict__ A, const unsigned short* __restrict__ Bm,
    float* __restrict__ C, const float* __restrict__ bias, int N_, int K_) {
  alignas(16) __shared__ unsigned short smA[128 * 64];
  alignas(16) __shared__ unsigned short smB[128 * 64];
  const int tid = threadIdx.x;
  const int lane = tid & 63;
  const int wv = tid >> 6;
  const int wm = wv >> 1, wn = wv & 1;
  const long m0 = (long)blockIdx.y * 128, n0 = (long)blockIdx.x * 128;

  const f32x4 zero4 = {0.f, 0.f, 0.f, 0.f};
  f32x4 acc[4][4];
#pragma unroll
  for (int i = 0; i < 4; ++i)
#pragma unroll
    for (int j = 0; j < 4; ++j) acc[i][j] = zero4;

  int mrow[4], gg[4];
#pragma unroll
  for (int w = 0; w < 4; ++w) {
    int c = w * 256 + tid;
    mrow[w] = c >> 3;
    gg[w] = (c & 7) ^ ((c >> 3) & 7);
  }

  const int kTiles = K_ >> 6;
  for (int kt = 0; kt < kTiles; ++kt) {
    if (kt) __syncthreads();
    const int kb = kt << 6;
#pragma unroll
    for (int w = 0; w < 4; ++w) {
      const int c = w * 256 + tid;
      async_copy16(A + (size_t)(m0 + mrow[w]) * K_ + kb + gg[w] * 8,
                   (char*)smA + c * 16);
      async_copy16(Bm + (size_t)(n0 + mrow[w]) * K_ + kb + gg[w] * 8,
                   (char*)smB + c * 16);
    }
    __syncthreads();
#pragma unroll
    for (int ks = 0; ks < 2; ++ks) {
      bf16x8 af[4], bg[4];
#pragma unroll
      for (int i = 0; i < 4; ++i) {
        const int ra = wm * 64 + i * 16 + (lane & 15);
        const int ga = (ks * 4 + (lane >> 4)) ^ (ra & 7);
        af[i] = *(const bf16x8*)((const char*)smA + ra * 128 + ga * 16);
        const int rb = wn * 64 + i * 16 + (lane & 15);
        const int gb2 = (ks * 4 + (lane >> 4)) ^ (rb & 7);
        bg[i] = *(const bf16x8*)((const char*)smB + rb * 128 + gb2 * 16);
      }
#pragma unroll
      for (int i = 0; i < 4; ++i)
#pragma unroll
        for (int j = 0; j < 4; ++j)
          acc[i][j] = __builtin_amdgcn_mfma_f32_16x16x32_bf16(af[i], bg[j], acc[i][j], 0, 0, 0);
    }
  }

  const int r0 = wm * 64 + (lane >> 4) * 4;
  const int c0 = wn * 64 + (lane & 15);
#pragma unroll
  for (int j = 0; j < 4; ++j) {
    const long col = n0 + c0 + j * 16;
    float bv = 0.f;
    if (HASBIAS) bv = bias[col];
#pragma unroll
    for (int i = 0; i < 4; ++i) {
#pragma unroll
      for (int r = 0; r < 4; ++r) {
        const long row = m0 + r0 + i * 16 + r;
        C[row * N_ + col] = acc[i][j][r] + bv;
      }
    }
  }
}

// prep: rotary q,k; norms; normalize h>=10; fold sscale*log2e into q (geom0/2);
// emit fragment-linear tiles. Q2: [hi|lo] 8 frags/qw. K2: hi-only 8 frags/ktile.
// V2: 8 frags/ktile.
__global__ __launch_bounds__(256) void prep(
    const float* __restrict__ qkvf, unsigned short* __restrict__ Q2,
    unsigned short* __restrict__ K2, unsigned short* __restrict__ V2,
    float* __restrict__ qq, float* __restrict__ kk, const float* __restrict__ curvg) {
  __shared__ unsigned short Vl[64 * 66];
  const int tid = threadIdx.x;
  const int zz = blockIdx.x;
  const int ttile = zz & 31, bh = zz >> 5;
  const int b = bh >> 4, h = bh & 15;
  const int t0 = ttile * 64;
  const int tr = tid >> 2, seg = tid & 3;
  const int t = t0 + tr;
  const float* src = qkvf + ((size_t)(b * 2048 + t)) * 3072 + h * 64 + seg * 16;

  float qv[16], kv[16], vv[16];
#pragma unroll
  for (int c = 0; c < 4; ++c) {
    const f32x4 a  = *(const f32x4*)(src + c * 4);
    const f32x4 bb = *(const f32x4*)(src + 1024 + c * 4);
    const f32x4 cc = *(const f32x4*)(src + 2048 + c * 4);
#pragma unroll
    for (int e = 0; e < 4; ++e) { qv[c*4+e] = a[e]; kv[c*4+e] = bb[e]; vv[c*4+e] = cc[e]; }
  }
  float qr[16], kr[16];
#pragma unroll
  for (int e = 0; e < 16; ++e) {
    const int d = seg * 16 + e;
    const int i = d & 31;
    const float invf = exp2f(-0.41524101186109286f * (float)i);  // 10000^(-i/32)
    float sn, cs;
    sincosf((float)t * invf, &sn, &cs);
    const float qo = __shfl_xor(qv[e], 2, 64);
    const float ko = __shfl_xor(kv[e], 2, 64);
    qr[e] = (d < 32) ? (qv[e] * cs + qo * sn) : (qv[e] * cs - qo * sn);
    kr[e] = (d < 32) ? (kv[e] * cs + ko * sn) : (kv[e] * cs - ko * sn);
  }
  float sq = 0.f, sk = 0.f;
#pragma unroll
  for (int e = 0; e < 16; ++e) { sq += qr[e] * qr[e]; sk += kr[e] * kr[e]; }
  sq += __shfl_xor(sq, 1, 64); sq += __shfl_xor(sq, 2, 64);
  sk += __shfl_xor(sk, 1, 64); sk += __shfl_xor(sk, 2, 64);
  float qscale = 0.125f * 1.4426950408889634f;   // geom0: fold sscale*log2e
  if (h >= 10) {
    const float rq = 1.0f / fmaxf(sqrtf(sq), 1e-12f);
    const float rk = 1.0f / fmaxf(sqrtf(sk), 1e-12f);
#pragma unroll
    for (int e = 0; e < 16; ++e) { qr[e] *= rq; kr[e] *= rk; }
    qscale = 8.0f * 1.4426950408889634f;         // geom2
  } else if (h >= 6) {
    qscale = 1.0f;                                // geom1: raw dot needed
  }
#pragma unroll
  for (int e = 0; e < 16; ++e) qr[e] *= qscale;
  if (seg == 0) {
    const int idx = b * 32768 + h * 2048 + t;
    float oq = sq, ok = sk;
    if (h >= 6 && h < 10) {
      const float invc = 1.0f / curvg[h - 6];
      oq = sqrtf(invc + sq);
      ok = sqrtf(invc + sk);
    }
    qq[idx] = oq;
    kk[idx] = ok;
  }
  const int st = seg >> 1;
  const int quadA = (seg * 2) & 3, quadB = (seg * 2 + 1) & 3;
  {
    unsigned int wh[8], wl[8];
#pragma unroll
    for (int p = 0; p < 8; ++p) {
      unsigned short h0 = f2bf(qr[2*p]), h1 = f2bf(qr[2*p+1]);
      unsigned short l0 = f2bf(qr[2*p] - bf2f(h0)), l1 = f2bf(qr[2*p+1] - bf2f(h1));
      wh[p] = (unsigned)h0 | ((unsigned)h1 << 16);
      wl[p] = (unsigned)l0 | ((unsigned)l1 << 16);
    }
    const int qi = (t >> 4) & 1, c15q = t & 15;
    unsigned short* qs = Q2 + ((size_t)bh * 64 + (t >> 5)) * 4096;
    const int fh = ((qi * 2 + st) * 2 + 0) * 512, fl = fh + 512;
    *(uint4*)(qs + fh + quadA * 128 + c15q * 8) = uint4{wh[0], wh[1], wh[2], wh[3]};
    *(uint4*)(qs + fh + quadB * 128 + c15q * 8) = uint4{wh[4], wh[5], wh[6], wh[7]};
    *(uint4*)(qs + fl + quadA * 128 + c15q * 8) = uint4{wl[0], wl[1], wl[2], wl[3]};
    *(uint4*)(qs + fl + quadB * 128 + c15q * 8) = uint4{wl[4], wl[5], wl[6], wl[7]};
    // K: hi frags only
#pragma unroll
    for (int p = 0; p < 8; ++p) {
      unsigned short h0 = f2bf(kr[2*p]), h1 = f2bf(kr[2*p+1]);
      wh[p] = (unsigned)h0 | ((unsigned)h1 << 16);
    }
    const int kj = (tr >> 4) & 3, c15k = tr & 15;
    unsigned short* ks = K2 + ((size_t)bh * 32 + ttile) * 4096;
    const int gh = (st * 4 + kj) * 512;
    *(uint4*)(ks + gh + quadA * 128 + c15k * 8) = uint4{wh[0], wh[1], wh[2], wh[3]};
    *(uint4*)(ks + gh + quadB * 128 + c15k * 8) = uint4{wh[4], wh[5], wh[6], wh[7]};
  }
#pragma unroll
  for (int e = 0; e < 16; ++e) Vl[(seg * 16 + e) * 66 + tr] = f2bf(vv[e]);
  __syncthreads();
  {
    const int d = tid >> 2, tch = (tid & 3) * 16;
    unsigned int wv2[8];
#pragma unroll
    for (int p = 0; p < 8; ++p) {
      const unsigned short a0 = Vl[d * 66 + tch + 2*p];
      const unsigned short a1 = Vl[d * 66 + tch + 2*p + 1];
      wv2[p] = (unsigned)a0 | ((unsigned)a1 << 16);
    }
    const int dj = d >> 4, c15v = d & 15;
    const int ks2 = tch >> 5;
    const int qvA = (tch >> 3) & 3, qvB = ((tch >> 3) + 1) & 3;
    unsigned short* vs = V2 + ((size_t)bh * 32 + ttile) * 4096 + (ks2 * 4 + dj) * 512;
    *(uint4*)(vs + qvA * 128 + c15v * 8) = uint4{wv2[0], wv2[1], wv2[2], wv2[3]};
    *(uint4*)(vs + qvB * 128 + c15v * 8) = uint4{wv2[4], wv2[5], wv2[6], wv2[7]};
  }
}

// Split-K barrier-free MFMA flash attention. 2-product scores; geom0/2 scale folded
// into q -> p = exp2(s), no Moff (cancels in o/l). bh-major block order (R12 win).
__global__ __launch_bounds__(64) void attn_part(
    const unsigned short* __restrict__ Q2, const unsigned short* __restrict__ K2,
    const unsigned short* __restrict__ V2, const float* __restrict__ tqq,
    const float* __restrict__ tkk, const float* __restrict__ curvg,
    float* __restrict__ part) {
  alignas(16) __shared__ unsigned short Pl[32 * 64];   // 4KB wave-private P tile
  const int lane = threadIdx.x;
  const int quad = lane >> 4, c15 = lane & 15;
  const int z = blockIdx.x;
  const int bh = z / 160;                // bh-major
  const int u = 159 - (z - bh * 160);    // big (qw,ch) first within the head
  int qw, ch;
  if (u < 16)      { qw = u; ch = 0; }
  else if (u < 48) { qw = 16 + ((u - 16) >> 1); ch = (u - 16) & 1; }
  else if (u < 96) { const int s2 = u - 48; const int q3 = s2 / 3; qw = 32 + q3; ch = s2 - 3 * q3; }
  else             { const int s2 = u - 96; qw = 48 + (s2 >> 2); ch = s2 & 3; }
  const int h = bh & 15;
  const int geom = (h < 6) ? 0 : ((h < 10) ? 1 : 2);
  const int qrow0 = qw * 32;
  const f32x4 zero4 = {0.f, 0.f, 0.f, 0.f};

  const unsigned short* qbase = Q2 + ((size_t)bh * 64 + qw) * 4096;
  bf16x8 qh[2][2], ql[2][2];
#pragma unroll
  for (int qi = 0; qi < 2; ++qi)
#pragma unroll
    for (int st = 0; st < 2; ++st) {
      const int f = ((qi * 2 + st) * 2) * 512 + lane * 8;
      qh[qi][st] = *(const bf16x8*)(qbase + f);
      ql[qi][st] = *(const bf16x8*)(qbase + f + 512);
    }

  float curv = 1.f, sic = 1.f;
  const float Moff = 4.0f;               // geom1 only
  f32x4 tq4[2] = {zero4, zero4};
  if (geom == 1) {
    curv = curvg[h - 6];
    sic = sqrtf(1.0f / curv);
#pragma unroll
    for (int qi = 0; qi < 2; ++qi)
      tq4[qi] = *(const f32x4*)(tqq + bh * 2048 + qrow0 + qi * 16 + quad * 4);
  }

  const __bf16 one_b = (__bf16)1.0f;
  const bf16x8 ones = {one_b, one_b, one_b, one_b, one_b, one_b, one_b, one_b};

  f32x4 o[2][4];
  f32x4 ol[2] = {zero4, zero4};
#pragma unroll
  for (int qi = 0; qi < 2; ++qi)
#pragma unroll
    for (int dj = 0; dj < 4; ++dj) o[qi][dj] = zero4;

  const int nkt = (qw >> 1) + 1;
  const int ktB = ch * 8;
  const int ktE = (ktB + 8 < nkt) ? (ktB + 8) : nkt;
  for (int kt = ktB; kt < ktE; ++kt) {
    const int kb = kt * 64;
    const unsigned short* kbase = K2 + ((size_t)bh * 32 + kt) * 4096;  // hi-only
    const unsigned short* vbase = V2 + ((size_t)bh * 32 + kt) * 4096;

    // ---- S = Q·K^T, 2-product (qh+ql)·kh
    f32x4 s[2][4];
#pragma unroll
    for (int qi = 0; qi < 2; ++qi)
#pragma unroll
      for (int kj = 0; kj < 4; ++kj) s[qi][kj] = zero4;
#pragma unroll
    for (int st = 0; st < 2; ++st) {
#pragma unroll
      for (int kj = 0; kj < 4; ++kj) {
        const bf16x8 bhf = *(const bf16x8*)(kbase + (st * 4 + kj) * 512 + lane * 8);
#pragma unroll
        for (int qi = 0; qi < 2; ++qi) {
          s[qi][kj] = __builtin_amdgcn_mfma_f32_16x16x32_bf16(qh[qi][st], bhf, s[qi][kj], 0, 0, 0);
          s[qi][kj] = __builtin_amdgcn_mfma_f32_16x16x32_bf16(ql[qi][st], bhf, s[qi][kj], 0, 0, 0);
        }
      }
    }

    // ---- p: geom0/2 -> exp2(s) (scale pre-folded, no Moff); geom1 -> full transform
    const bool needmask = (kt == nkt - 1);
#pragma unroll
    for (int qi = 0; qi < 2; ++qi) {
      const int qbaserow = qrow0 + qi * 16 + quad * 4;
#pragma unroll
      for (int kj = 0; kj < 4; ++kj) {
        const int skey = kj * 16 + c15;
        const int key = kb + skey;
        const f32x4 d4 = s[qi][kj];
        f32x4 p;
        if (geom == 1) {
          const float tk = tkk[bh * 2048 + key];
#pragma unroll
          for (int r = 0; r < 4; ++r) {
            const float a = fmaxf(curv * (tq4[qi][r] * tk - d4[r]), 1.0f + 1e-7f);
            const float dis = sic * __logf(a + sqrtf(a * a - 1.0f));
            p[r] = __expf(__builtin_amdgcn_rcpf(1e-6f + dis) - Moff);
          }
        } else {
#pragma unroll
          for (int r = 0; r < 4; ++r) p[r] = exp2f(d4[r]);
        }
        if (needmask) {
#pragma unroll
          for (int r = 0; r < 4; ++r)
            if (key > qbaserow + r) p[r] = 0.0f;
        }
#pragma unroll
        for (int r = 0; r < 4; ++r) {
          union { float f; unsigned u2; } pv; pv.f = p[r];
          const int row = qi * 16 + quad * 4 + r;
          const int g = (skey >> 3) ^ (row & 7);
          Pl[row * 64 + g * 8 + (skey & 7)] = (unsigned short)(pv.u2 >> 16);
        }
      }
    }

    // ---- PV: O += P·V^T ; l += P·1
#pragma unroll
    for (int ks2 = 0; ks2 < 2; ++ks2) {
      bf16x8 av[2];
#pragma unroll
      for (int qi = 0; qi < 2; ++qi) {
        const int m = qi * 16 + c15;
        const int g = (ks2 * 4 + quad) ^ (m & 7);
        av[qi] = *(const bf16x8*)(Pl + m * 64 + g * 8);
        ol[qi] = __builtin_amdgcn_mfma_f32_16x16x32_bf16(av[qi], ones, ol[qi], 0, 0, 0);
      }
#pragma unroll
      for (int dj = 0; dj < 4; ++dj) {
        const bf16x8 bv = *(const bf16x8*)(vbase + (ks2 * 4 + dj) * 512 + lane * 8);
#pragma unroll
        for (int qi = 0; qi < 2; ++qi)
          o[qi][dj] = __builtin_amdgcn_mfma_f32_16x16x32_bf16(av[qi], bv, o[qi][dj], 0, 0, 0);
      }
    }
  }

  // ---- partial write: slot = bh*160 + u, stride 2112 f32
  float* slot = part + (size_t)(bh * 160 + u) * 2112;
#pragma unroll
  for (int qi = 0; qi < 2; ++qi)
#pragma unroll
    for (int dj = 0; dj < 4; ++dj)
      *(f32x4*)(slot + (qi * 4 + dj) * 256 + lane * 4) = o[qi][dj];
  if (c15 == 0) {
#pragma unroll
    for (int qi = 0; qi < 2; ++qi)
      *(f32x4*)(slot + 2048 + qi * 16 + quad * 4) = ol[qi];
  }
}

// Sum chunk partials, divide, LDS-transpose, write A'y [hi|lo] (2048-wide).
__global__ __launch_bounds__(64) void attn_reduce(
    const float* __restrict__ part, unsigned short* __restrict__ Ay) {
  __shared__ float Ol[32 * 65];
  const int lane = threadIdx.x;
  const int quad = lane >> 4, c15 = lane & 15;
  const int z = blockIdx.x, bh = z & 31, qw = 63 - (z >> 5);
  const int b = bh >> 4, h = bh & 15;
  const int G = qw >> 4;
  const int base = qw + 8 * G * (G - 1) + (qw & 15) * G;
  const float* slot0 = part + (size_t)(bh * 160 + base) * 2112;

  const f32x4 zero4 = {0.f, 0.f, 0.f, 0.f};
  f32x4 o[8];
  f32x4 l4[2] = {zero4, zero4};
#pragma unroll
  for (int i = 0; i < 8; ++i) o[i] = zero4;
  for (int chv = 0; chv <= G; ++chv) {
    const float* sl = slot0 + chv * 2112;
#pragma unroll
    for (int i = 0; i < 8; ++i) o[i] += *(const f32x4*)(sl + i * 256 + lane * 4);
#pragma unroll
    for (int qi = 0; qi < 2; ++qi)
      l4[qi] += *(const f32x4*)(sl + 2048 + qi * 16 + quad * 4);
  }
#pragma unroll
  for (int qi = 0; qi < 2; ++qi) {
    f32x4 invl;
#pragma unroll
    for (int r = 0; r < 4; ++r) invl[r] = __builtin_amdgcn_rcpf(l4[qi][r]);
#pragma unroll
    for (int dj = 0; dj < 4; ++dj) {
      const f32x4 val = o[qi * 4 + dj] * invl;
#pragma unroll
      for (int r = 0; r < 4; ++r)
        Ol[(qi * 16 + quad * 4 + r) * 65 + dj * 16 + c15] = val[r];
    }
  }
  __syncthreads();
  const int row = lane >> 1, half = lane & 1;
  const float* rp = Ol + row * 65 + half * 32;
  unsigned int uh[16], ul2[16];
#pragma unroll
  for (int p = 0; p < 16; ++p) {
    const float v0 = rp[2 * p], v1 = rp[2 * p + 1];
    const unsigned short h0 = f2bf(v0), h1 = f2bf(v1);
    const unsigned short g0 = f2bf(v0 - bf2f(h0)), g1 = f2bf(v1 - bf2f(h1));
    uh[p] = (unsigned)h0 | ((unsigned)h1 << 16);
    ul2[p] = (unsigned)g0 | ((unsigned)g1 << 16);
  }
  unsigned short* yp = Ay + ((size_t)(b * 2048 + qw * 32 + row)) * 2048 + h * 64 + half * 32;
#pragma unroll
  for (int c = 0; c < 4; ++c) {
    *(uint4*)(yp + 8 * c)        = uint4{uh[4*c], uh[4*c+1], uh[4*c+2], uh[4*c+3]};
    *(uint4*)(yp + 1024 + 8 * c) = uint4{ul2[4*c], ul2[4*c+1], ul2[4*c+2], ul2[4*c+3]};
  }
}

extern "C" void kernel_launch(void* const* d_in, const int* in_sizes, int n_in,
                              void* d_out, int out_size, void* d_ws, size_t ws_size,
                              hipStream_t stream) {
  const float* x      = (const float*)d_in[0];
  const float* qkv_w  = (const float*)d_in[1];
  const float* proj_w = (const float*)d_in[2];
  const float* proj_b = (const float*)d_in[3];
  const float* curvature = (const float*)d_in[4];
  float* out = (float*)d_out;

  char* ws = (char*)d_ws;
  unsigned short* AX   = (unsigned short*)ws;                     // 4096x2048 bf16
  unsigned short* BW   = (unsigned short*)(ws + 16777216);        // 3072x2048 bf16
  float*          QKVF = (float*)(ws + 33554432);                 // 4096x3072 f32
  unsigned short* Q2   = (unsigned short*)ws;                     // 16MB
  unsigned short* K2   = (unsigned short*)(ws + 16777216);        // 8MB (hi-only)
  unsigned short* V2   = (unsigned short*)(ws + 25165824);        // 8MB
  float*          PART = (float*)(ws + 33554432);                 // 43,253,760 B
  unsigned short* BPW  = (unsigned short*)(ws + 76808192);        // 1024x2048 bf16
  unsigned short* AY   = (unsigned short*)ws;                     // 4096x2048 bf16
  float*          QQ   = (float*)(ws + 94371840);
  float*          KK   = (float*)(ws + 94633984);

  split2<0><<<4096, 256, 0, stream>>>(x, AX);
  split2<1><<<3072, 256, 0, stream>>>(qkv_w, BW);

  gemm_bt<0><<<dim3(24, 32), 256, 0, stream>>>(AX, BW, QKVF, nullptr, 3072, 2048);

  prep<<<1024, 256, 0, stream>>>(QKVF, Q2, K2, V2, QQ, KK, curvature);

  split2<1><<<1024, 256, 0, stream>>>(proj_w, BPW);   // after prep: QKVF region free

  attn_part<<<5120, 64, 0, stream>>>(Q2, K2, V2, QQ, KK, curvature, PART);

  attn_reduce<<<2048, 64, 0, stream>>>(PART, AY);

  gemm_bt<1><<<dim3(8, 32), 256, 0, stream>>>(AY, BPW, out, proj_b, 1024, 2048);
}